// Round 2
// baseline (165.076 us; speedup 1.0000x reference)
//
#include <hip/hip_runtime.h>
#include <stdint.h>

// ---- types ----
typedef __attribute__((ext_vector_type(4))) float   f4;
typedef __attribute__((ext_vector_type(8))) short   short8;   // 8 x bf16 (MFMA A/B frag)
typedef __attribute__((ext_vector_type(4))) float   floatx4;  // MFMA C/D frag
typedef __attribute__((ext_vector_type(4))) unsigned int u32x4;

#define LN2F 0.6931471805599453f

// Problem constants
#define BB 65536
#define SS 512
#define DD 100
// K padded to 128 (4 k-steps of 32 for mfma 16x16x32 bf16)

__device__ __forceinline__ unsigned short f2bf(float f) {
  union { float f; unsigned int u; } v; v.f = f;
  unsigned int u = v.u;
  u += 0x7fffu + ((u >> 16) & 1u);   // RNE
  return (unsigned short)(u >> 16);
}
__device__ __forceinline__ float bf2f(short s) {
  union { float f; unsigned int u; } v;
  v.u = ((unsigned int)(unsigned short)s) << 16;
  return v.f;
}
__device__ __forceinline__ u32x4 pack8(f4 a, f4 b) {
  u32x4 r;
  r.x = (unsigned int)f2bf(a[0]) | ((unsigned int)f2bf(a[1]) << 16);
  r.y = (unsigned int)f2bf(a[2]) | ((unsigned int)f2bf(a[3]) << 16);
  r.z = (unsigned int)f2bf(b[0]) | ((unsigned int)f2bf(b[1]) << 16);
  r.w = (unsigned int)f2bf(b[2]) | ((unsigned int)f2bf(b[3]) << 16);
  return r;
}
// numerically stable softplus(x) = log(1+e^x)
__device__ __forceinline__ float softplus_full(float x) {
  return fmaxf(x, 0.f) + log1pf(expf(-fabsf(x)));
}

// ---------------------------------------------------------------------------
// Kernel 1: gather + convert neg rows into MFMA B-fragment tiled layout in ws.
// Layout: 16B unit index = (sgroup*4 + kstep)*64 + (s&15) + 16*kquad
// Also zero-inits out[0] (d_out is poisoned 0xAA each iteration; keg_main
// accumulates into it atomically).
// ---------------------------------------------------------------------------
__global__ __launch_bounds__(256) void negprep_k(
    const float* __restrict__ tail_table, const int* __restrict__ neg_idx,
    u32x4* __restrict__ nws, float* __restrict__ out) {
  if (blockIdx.x == 0 && threadIdx.x == 0) out[0] = 0.f;
  int tid = blockIdx.x * 256 + threadIdx.x;          // 32 blocks -> 8192 threads
  int s = tid >> 4, kg = tid & 15, k0 = kg * 8;      // 16 threads per s-row
  int nrow = neg_idx[s];
  const float* np = tail_table + (size_t)nrow * DD;  // rows are 400B = 16B aligned
  f4 a = {0.f,0.f,0.f,0.f}, b = {0.f,0.f,0.f,0.f};
  if (kg < 12)       { a = *(const f4*)(np + k0); b = *(const f4*)(np + k0 + 4); }
  else if (kg == 12) { a = *(const f4*)(np + 96); }   // k 96..99 valid, 100..103 pad
  nws[((s >> 4) * 4 + (kg >> 2)) * 64 + (s & 15) + 16 * (kg & 3)] = pack8(a, b);
}

// ---------------------------------------------------------------------------
// Kernel 2: fused main. Block = 256 thr (4 waves) handles 64 b-rows x all 512 s.
//   stage1: gather ex = head[h_idx]+rel into LDS A-frag layout (bf16, K->128 pad)
//   pos   : each wave does 16 rows' pos loss
//   neg   : 8 n-groups/wave; bias pre-folded into MFMA C-init; guarded softplus
//   block partial -> atomicAdd(out, partial/65536)
// ---------------------------------------------------------------------------
__global__ __launch_bounds__(256, 3) void keg_main(
    const float* __restrict__ head_table, const float* __restrict__ tail_table,
    const float* __restrict__ rel_vec,   const float* __restrict__ rel_bias,
    const int* __restrict__ head_idx,    const int* __restrict__ tail_idx,
    const u32x4* __restrict__ nws,       float* __restrict__ out) {
  __shared__ u32x4 exA4[1024];   // 64 rows x 128 k, A-frag tiled: 16KB
  __shared__ float bias_s[64];
  __shared__ float red[4];

  const int t = threadIdx.x;
  const int kg = t & 15, k0 = kg * 8, rid = t >> 4;
  const int bbase = blockIdx.x * 64;

  // ---- stage 1: gather ex into LDS (A-fragment layout), stash bias ----
  #pragma unroll
  for (int p = 0; p < 4; ++p) {
    int r  = p * 16 + rid;            // local row 0..63
    int gb = bbase + r;
    int hrow = head_idx[gb];
    const float* hp = head_table + (size_t)hrow * DD;
    f4 a = {0,0,0,0}, b = {0,0,0,0}, ra = {0,0,0,0}, rb = {0,0,0,0};
    if (kg < 12) {
      a  = *(const f4*)(hp + k0);       b  = *(const f4*)(hp + k0 + 4);
      ra = *(const f4*)(rel_vec + k0);  rb = *(const f4*)(rel_vec + k0 + 4);
    } else if (kg == 12) {
      a  = *(const f4*)(hp + 96);       ra = *(const f4*)(rel_vec + 96);
    }
    f4 e0 = a + ra, e1 = b + rb;
    exA4[(p * 4 + (kg >> 2)) * 64 + rid + 16 * (kg & 3)] = pack8(e0, e1);
    if (kg == 0) bias_s[r] = rel_bias[tail_idx[gb]];
  }
  __syncthreads();

  const int w = t >> 6, lane = t & 63;
  const int m15 = lane & 15, quad = lane >> 4;
  const short8* exAs = (const short8*)exA4;

  // ---- pos part: wave w handles rows w*16 .. w*16+15 ----
  float pos_acc = 0.f;
  {
    int rloc = w * 16 + m15;
    int gb = bbase + rloc;
    int trow = tail_idx[gb];
    const float* tp = tail_table + (size_t)trow * DD;
    float pdot = 0.f;
    #pragma unroll
    for (int ks = 0; ks < 4; ++ks) {
      short8 ev = exAs[(w * 4 + ks) * 64 + lane];  // row m15, k = ks*32+quad*8..+7
      int kk = ks * 32 + quad * 8;
      f4 ta = {0,0,0,0}, tb = {0,0,0,0};
      if (kk < 96)       { ta = *(const f4*)(tp + kk); tb = *(const f4*)(tp + kk + 4); }
      else if (kk == 96) { ta = *(const f4*)(tp + 96); }
      pdot += bf2f(ev[0])*ta[0] + bf2f(ev[1])*ta[1] + bf2f(ev[2])*ta[2] + bf2f(ev[3])*ta[3];
      pdot += bf2f(ev[4])*tb[0] + bf2f(ev[5])*tb[1] + bf2f(ev[6])*tb[2] + bf2f(ev[7])*tb[3];
    }
    pdot += __shfl_xor(pdot, 16);
    pdot += __shfl_xor(pdot, 32);
    if (lane < 16) {
      float logit = pdot + bias_s[rloc];
      pos_acc = softplus_full(-logit);   // -log_sigmoid(logit)
    }
  }

  // ---- neg part ----
  short8 afr[4][4];
  #pragma unroll
  for (int mf = 0; mf < 4; ++mf)
    #pragma unroll
    for (int ks = 0; ks < 4; ++ks)
      afr[mf][ks] = exAs[(mf * 4 + ks) * 64 + lane];

  float biasr[4][4];   // bias for C rows: m = mf*16 + quad*4 + r
  #pragma unroll
  for (int mf = 0; mf < 4; ++mf)
    #pragma unroll
    for (int r2 = 0; r2 < 4; ++r2)
      biasr[mf][r2] = bias_s[mf * 16 + quad * 4 + r2];

  const short8* nfr = (const short8*)nws;
  float nacc = 0.f;
  #pragma unroll 2
  for (int g = 0; g < 8; ++g) {          // wave w: s-groups w*8 .. w*8+7
    int ng = w * 8 + g;
    short8 bfr[4];
    #pragma unroll
    for (int ks = 0; ks < 4; ++ks)
      bfr[ks] = nfr[(ng * 4 + ks) * 64 + lane];  // coalesced, L2-hot
    floatx4 acc[4];
    #pragma unroll
    for (int mf = 0; mf < 4; ++mf) {     // bias pre-folded into C-init
      floatx4 c;
      c[0] = biasr[mf][0]; c[1] = biasr[mf][1];
      c[2] = biasr[mf][2]; c[3] = biasr[mf][3];
      acc[mf] = c;
    }
    #pragma unroll
    for (int ks = 0; ks < 4; ++ks)
      #pragma unroll
      for (int mf = 0; mf < 4; ++mf)
        acc[mf] = __builtin_amdgcn_mfma_f32_16x16x32_bf16(afr[mf][ks], bfr[ks], acc[mf], 0, 0, 0);
    // epilogue: acc already = logits; min/max chains (fold to v_max3/v_min3)
    float mx = acc[0][0], mn = acc[0][0];
    #pragma unroll
    for (int mf = 0; mf < 4; ++mf)
      #pragma unroll
      for (int r2 = 0; r2 < 4; ++r2) {
        float x = acc[mf][r2];
        mx = fmaxf(mx, x); mn = fminf(mn, x);
      }
    bool small = (mx < 0.03f) && (mn > -0.03f);
    if (__ballot(small) == ~0ULL) {
      // deg-2 Taylor: softplus(x) = ln2 + x/2 + x^2/8, |err| < 5e-9 for |x|<0.03
      float s2 = 0.f;
      #pragma unroll
      for (int mf = 0; mf < 4; ++mf)
        #pragma unroll
        for (int r2 = 0; r2 < 4; ++r2) {
          float x = acc[mf][r2];
          s2 = fmaf(x, fmaf(x, 0.125f, 0.5f), s2);
        }
      nacc += s2 + 16.f * LN2F;
    } else {
      #pragma unroll
      for (int mf = 0; mf < 4; ++mf)
        #pragma unroll
        for (int r2 = 0; r2 < 4; ++r2)
          nacc += softplus_full(acc[mf][r2]);
    }
  }

  // ---- block reduce -> atomic accumulate (scaled by exact pow2 1/BB) ----
  float tot = nacc + pos_acc;
  #pragma unroll
  for (int off = 32; off; off >>= 1) tot += __shfl_down(tot, off);
  if (lane == 0) red[w] = tot;
  __syncthreads();
  if (t == 0)
    atomicAdd(out, (red[0] + red[1] + red[2] + red[3]) * (1.0f / (float)BB));
}

extern "C" void kernel_launch(void* const* d_in, const int* in_sizes, int n_in,
                              void* d_out, int out_size, void* d_ws, size_t ws_size,
                              hipStream_t stream) {
  const float* head_table = (const float*)d_in[0];
  const float* tail_table = (const float*)d_in[1];
  const float* rel_vec    = (const float*)d_in[2];
  const float* rel_bias   = (const float*)d_in[3];
  const int*   head_idx   = (const int*)d_in[4];
  const int*   tail_idx   = (const int*)d_in[5];
  const int*   neg_idx    = (const int*)d_in[6];
  float* out = (float*)d_out;

  u32x4* nws = (u32x4*)d_ws;                 // 512 x 128 bf16 = 131072 B

  negprep_k<<<32, 256, 0, stream>>>(tail_table, neg_idx, nws, out);
  keg_main<<<1024, 256, 0, stream>>>(head_table, tail_table, rel_vec, rel_bias,
                                     head_idx, tail_idx, (const u32x4*)nws, out);
}

// Round 3
// 162.166 us; speedup vs baseline: 1.0179x; 1.0179x over previous
//
#include <hip/hip_runtime.h>
#include <stdint.h>

// ---- types ----
typedef __attribute__((ext_vector_type(4))) float   f4;
typedef __attribute__((ext_vector_type(8))) short   short8;   // 8 x bf16 (MFMA A/B frag)
typedef __attribute__((ext_vector_type(4))) float   floatx4;  // MFMA C/D frag
typedef __attribute__((ext_vector_type(4))) unsigned int u32x4;

#define LN2F 0.6931471805599453f

// Problem constants
#define BB 65536
#define SS 512
#define DD 100
// K padded to 128 (4 k-steps of 32 for mfma 16x16x32 bf16)

__device__ __forceinline__ unsigned short f2bf(float f) {
  union { float f; unsigned int u; } v; v.f = f;
  unsigned int u = v.u;
  u += 0x7fffu + ((u >> 16) & 1u);   // RNE
  return (unsigned short)(u >> 16);
}
__device__ __forceinline__ float bf2f(short s) {
  union { float f; unsigned int u; } v;
  v.u = ((unsigned int)(unsigned short)s) << 16;
  return v.f;
}
__device__ __forceinline__ u32x4 pack8(f4 a, f4 b) {
  u32x4 r;
  r.x = (unsigned int)f2bf(a[0]) | ((unsigned int)f2bf(a[1]) << 16);
  r.y = (unsigned int)f2bf(a[2]) | ((unsigned int)f2bf(a[3]) << 16);
  r.z = (unsigned int)f2bf(b[0]) | ((unsigned int)f2bf(b[1]) << 16);
  r.w = (unsigned int)f2bf(b[2]) | ((unsigned int)f2bf(b[3]) << 16);
  return r;
}
// numerically stable softplus(x) = log(1+e^x)
__device__ __forceinline__ float softplus_full(float x) {
  return fmaxf(x, 0.f) + log1pf(expf(-fabsf(x)));
}

// ---------------------------------------------------------------------------
// Kernel 1: gather + convert neg rows into MFMA B-fragment tiled layout in ws.
// Layout: 16B unit index = (sgroup*4 + kstep)*64 + (s&15) + 16*kquad
// Also zero-inits out[0] (d_out is poisoned 0xAA each iteration; keg_main
// accumulates into it atomically).
// ---------------------------------------------------------------------------
__global__ __launch_bounds__(256) void negprep_k(
    const float* __restrict__ tail_table, const int* __restrict__ neg_idx,
    u32x4* __restrict__ nws, float* __restrict__ out) {
  if (blockIdx.x == 0 && threadIdx.x == 0) out[0] = 0.f;
  int tid = blockIdx.x * 256 + threadIdx.x;          // 32 blocks -> 8192 threads
  int s = tid >> 4, kg = tid & 15, k0 = kg * 8;      // 16 threads per s-row
  int nrow = neg_idx[s];
  const float* np = tail_table + (size_t)nrow * DD;  // rows are 400B = 16B aligned
  f4 a = {0.f,0.f,0.f,0.f}, b = {0.f,0.f,0.f,0.f};
  if (kg < 12)       { a = *(const f4*)(np + k0); b = *(const f4*)(np + k0 + 4); }
  else if (kg == 12) { a = *(const f4*)(np + 96); }   // k 96..99 valid, 100..103 pad
  nws[((s >> 4) * 4 + (kg >> 2)) * 64 + (s & 15) + 16 * (kg & 3)] = pack8(a, b);
}

// ---------------------------------------------------------------------------
// Neg-matmul pass, register-lean: outer loop over 2 mf-halves (A-frags for a
// half = 32 VGPRs), inner over this wave's 8 s-groups. Fast variant is
// branchless (Taylor moments sx, sxx + running max|x|); full variant redoes
// everything with exact softplus (cold path, noinline).
// ---------------------------------------------------------------------------
__device__ __forceinline__ float neg_pass_fast(
    const short8* __restrict__ exAs, const short8* __restrict__ nfr,
    const float* __restrict__ bias_s, int w, int lane, int quad, float& amax) {
  float sx = 0.f, sxx = 0.f;
  amax = 0.f;
  #pragma unroll
  for (int h = 0; h < 2; ++h) {
    short8 afr[2][4];
    float  br[2][4];
    #pragma unroll
    for (int m = 0; m < 2; ++m) {
      int mf = h * 2 + m;
      #pragma unroll
      for (int ks = 0; ks < 4; ++ks) afr[m][ks] = exAs[(mf * 4 + ks) * 64 + lane];
      #pragma unroll
      for (int r = 0; r < 4; ++r)   br[m][r]  = bias_s[mf * 16 + quad * 4 + r];
    }
    #pragma unroll 2
    for (int g = 0; g < 8; ++g) {
      int ng = w * 8 + g;
      short8 bfr[4];
      #pragma unroll
      for (int ks = 0; ks < 4; ++ks)
        bfr[ks] = nfr[(ng * 4 + ks) * 64 + lane];   // coalesced, L2-hot
      floatx4 acc[2];
      #pragma unroll
      for (int m = 0; m < 2; ++m) {                 // bias folded into C-init
        floatx4 c; c[0] = br[m][0]; c[1] = br[m][1]; c[2] = br[m][2]; c[3] = br[m][3];
        acc[m] = c;
      }
      #pragma unroll
      for (int ks = 0; ks < 4; ++ks)
        #pragma unroll
        for (int m = 0; m < 2; ++m)
          acc[m] = __builtin_amdgcn_mfma_f32_16x16x32_bf16(afr[m][ks], bfr[ks], acc[m], 0, 0, 0);
      #pragma unroll
      for (int m = 0; m < 2; ++m)
        #pragma unroll
        for (int r = 0; r < 4; ++r) {
          float x = acc[m][r];
          sx += x;
          sxx = fmaf(x, x, sxx);
          amax = fmaxf(amax, fabsf(x));   // fabs folds to input modifier
        }
    }
  }
  // Sum of deg-2 Taylor softplus over all 128 elements this lane produced:
  // softplus(x) ~= ln2 + x/2 + x^2/8, |err| < 5e-9 for |x| < 0.03
  return fmaf(sx, 0.5f, fmaf(sxx, 0.125f, 128.f * LN2F));
}

__device__ __attribute__((noinline)) float neg_pass_full(
    const short8* __restrict__ exAs, const short8* __restrict__ nfr,
    const float* __restrict__ bias_s, int w, int lane, int quad) {
  float nacc = 0.f;
  for (int h = 0; h < 2; ++h) {
    short8 afr[2][4];
    float  br[2][4];
    for (int m = 0; m < 2; ++m) {
      int mf = h * 2 + m;
      for (int ks = 0; ks < 4; ++ks) afr[m][ks] = exAs[(mf * 4 + ks) * 64 + lane];
      for (int r = 0; r < 4; ++r)   br[m][r]  = bias_s[mf * 16 + quad * 4 + r];
    }
    for (int g = 0; g < 8; ++g) {
      int ng = w * 8 + g;
      short8 bfr[4];
      for (int ks = 0; ks < 4; ++ks) bfr[ks] = nfr[(ng * 4 + ks) * 64 + lane];
      floatx4 acc[2];
      for (int m = 0; m < 2; ++m) {
        floatx4 c; c[0] = br[m][0]; c[1] = br[m][1]; c[2] = br[m][2]; c[3] = br[m][3];
        acc[m] = c;
      }
      for (int ks = 0; ks < 4; ++ks)
        for (int m = 0; m < 2; ++m)
          acc[m] = __builtin_amdgcn_mfma_f32_16x16x32_bf16(afr[m][ks], bfr[ks], acc[m], 0, 0, 0);
      for (int m = 0; m < 2; ++m)
        for (int r = 0; r < 4; ++r)
          nacc += softplus_full(acc[m][r]);
    }
  }
  return nacc;
}

// ---------------------------------------------------------------------------
// Kernel 2: fused main. Block = 256 thr (4 waves) handles 64 b-rows x all 512 s.
// __launch_bounds__(256,4): 128-VGPR cap -> 16 waves/CU -> entire 1024-block
// grid co-resident (4 blocks/CU). Register-lean neg loop keeps A-frags in
// VGPRs (R2's VGPR=76 proved the compiler was re-reading them from LDS every
// s-group, serializing on the LDS pipe).
// ---------------------------------------------------------------------------
__global__ __launch_bounds__(256, 4) void keg_main(
    const float* __restrict__ head_table, const float* __restrict__ tail_table,
    const float* __restrict__ rel_vec,   const float* __restrict__ rel_bias,
    const int* __restrict__ head_idx,    const int* __restrict__ tail_idx,
    const u32x4* __restrict__ nws,       float* __restrict__ out) {
  __shared__ u32x4 exA4[1024];   // 64 rows x 128 k, A-frag tiled: 16KB
  __shared__ float bias_s[64];
  __shared__ float red[4];

  const int t = threadIdx.x;
  const int kg = t & 15, k0 = kg * 8, rid = t >> 4;
  const int bbase = blockIdx.x * 64;

  // ---- stage 1: gather ex = head+rel into LDS (A-frag layout), stash bias ----
  #pragma unroll
  for (int p = 0; p < 4; ++p) {
    int r  = p * 16 + rid;            // local row 0..63
    int gb = bbase + r;
    int hrow = head_idx[gb];
    const float* hp = head_table + (size_t)hrow * DD;
    f4 a = {0,0,0,0}, b = {0,0,0,0}, ra = {0,0,0,0}, rb = {0,0,0,0};
    if (kg < 12) {
      a  = *(const f4*)(hp + k0);       b  = *(const f4*)(hp + k0 + 4);
      ra = *(const f4*)(rel_vec + k0);  rb = *(const f4*)(rel_vec + k0 + 4);
    } else if (kg == 12) {
      a  = *(const f4*)(hp + 96);       ra = *(const f4*)(rel_vec + 96);
    }
    f4 e0 = a + ra, e1 = b + rb;
    exA4[(p * 4 + (kg >> 2)) * 64 + rid + 16 * (kg & 3)] = pack8(e0, e1);
    if (kg == 0) bias_s[r] = rel_bias[tail_idx[gb]];
  }
  __syncthreads();

  const int w = t >> 6, lane = t & 63;
  const int m15 = lane & 15, quad = lane >> 4;
  const short8* exAs = (const short8*)exA4;

  // ---- pos part: wave w handles rows w*16 .. w*16+15 ----
  float pos_acc = 0.f;
  {
    int rloc = w * 16 + m15;
    int gb = bbase + rloc;
    int trow = tail_idx[gb];
    const float* tp = tail_table + (size_t)trow * DD;
    float pdot = 0.f;
    #pragma unroll
    for (int ks = 0; ks < 4; ++ks) {
      short8 ev = exAs[(w * 4 + ks) * 64 + lane];  // row m15, k = ks*32+quad*8..+7
      int kk = ks * 32 + quad * 8;
      f4 ta = {0,0,0,0}, tb = {0,0,0,0};
      if (kk < 96)       { ta = *(const f4*)(tp + kk); tb = *(const f4*)(tp + kk + 4); }
      else if (kk == 96) { ta = *(const f4*)(tp + 96); }
      pdot += bf2f(ev[0])*ta[0] + bf2f(ev[1])*ta[1] + bf2f(ev[2])*ta[2] + bf2f(ev[3])*ta[3];
      pdot += bf2f(ev[4])*tb[0] + bf2f(ev[5])*tb[1] + bf2f(ev[6])*tb[2] + bf2f(ev[7])*tb[3];
    }
    pdot += __shfl_xor(pdot, 16);
    pdot += __shfl_xor(pdot, 32);
    if (lane < 16) {
      float logit = pdot + bias_s[rloc];
      pos_acc = softplus_full(-logit);   // -log_sigmoid(logit)
    }
  }

  // ---- neg part ----
  const short8* nfr = (const short8*)nws;
  float amax;
  float nacc = neg_pass_fast(exAs, nfr, bias_s, w, lane, quad, amax);
  if (__ballot(amax < 0.03f) != ~0ULL)
    nacc = neg_pass_full(exAs, nfr, bias_s, w, lane, quad);  // cold exact path

  // ---- block reduce -> atomic accumulate (scaled by exact pow2 1/BB) ----
  float tot = nacc + pos_acc;
  #pragma unroll
  for (int off = 32; off; off >>= 1) tot += __shfl_down(tot, off);
  if (lane == 0) red[w] = tot;
  __syncthreads();
  if (t == 0)
    atomicAdd(out, (red[0] + red[1] + red[2] + red[3]) * (1.0f / (float)BB));
}

extern "C" void kernel_launch(void* const* d_in, const int* in_sizes, int n_in,
                              void* d_out, int out_size, void* d_ws, size_t ws_size,
                              hipStream_t stream) {
  const float* head_table = (const float*)d_in[0];
  const float* tail_table = (const float*)d_in[1];
  const float* rel_vec    = (const float*)d_in[2];
  const float* rel_bias   = (const float*)d_in[3];
  const int*   head_idx   = (const int*)d_in[4];
  const int*   tail_idx   = (const int*)d_in[5];
  const int*   neg_idx    = (const int*)d_in[6];
  float* out = (float*)d_out;

  u32x4* nws = (u32x4*)d_ws;                 // 512 x 128 bf16 = 131072 B

  negprep_k<<<32, 256, 0, stream>>>(tail_table, neg_idx, nws, out);
  keg_main<<<1024, 256, 0, stream>>>(head_table, tail_table, rel_vec, rel_bias,
                                     head_idx, tail_idx, (const u32x4*)nws, out);
}